// Round 3
// baseline (186.957 us; speedup 1.0000x reference)
//
#include <hip/hip_runtime.h>
#include <hip/hip_bf16.h>

// Sparse Conv3d(32,32,k=2,s=2) kernel-map form:
//   out[out_idx[p], d] += sum_c x[p,c] * W[k_idx[p], c, d]
//
// R3: same atomic-free inverse-map design as R2 (each input point owns a
// unique (out_voxel, k) slot -> child[o][k]=p built with plain stores; one
// wave per 16 output voxels gathers children, 16x16x32 bf16 MFMA per k,
// plain-stores finished rows). Changes vs R2:
//  - child-map fill (-1) fused into prep kernel (grid-stride int4), 4->3 launches
//  - bf16 pack via __float22bfloat162_rn (v_cvt_pk_bf16_f32 on gfx950)
//    instead of ~5-VALU manual RNE per value

typedef __attribute__((ext_vector_type(8))) short bf16x8;   // 8 bf16 = 4 VGPRs
typedef __attribute__((ext_vector_type(4))) float f32x4;    // 4 fp32 acc

union ABFrag { bf16x8 v; int i[4]; };
union BFI { __hip_bfloat162 h; int i; };

__device__ __forceinline__ int pack2_bf16(float a, float b) {
    BFI u; u.h = __float22bfloat162_rn(make_float2(a, b));   // h.x=lo, h.y=hi
    return u.i;
}

__device__ __forceinline__ unsigned short f2bf(float f) {
    union { float f; unsigned u; } v; v.f = f;
    unsigned r = v.u + 0x7FFFu + ((v.u >> 16) & 1u);   // RNE
    return (unsigned short)(r >> 16);
}

// Fused: (a) repack W[k][c][d] fp32 -> WB in B-fragment lane order (16 KB):
// WB[((k*2+half)*64 + lane)*8 + j] = bf16(W[k][(lane>>4)*8+j][half*16+(lane&15)])
// (b) grid-stride fill of child map with -1 (int4 stores).
__global__ __launch_bounds__(256) void prep_fill_kernel(
    const float* __restrict__ W, unsigned short* __restrict__ WB,
    int4* __restrict__ child4, int n4) {
    int t = blockIdx.x * blockDim.x + threadIdx.x;
    if (t < 8 * 2 * 64 * 8) {
        int j    = t & 7;
        int lane = (t >> 3) & 63;
        int half = (t >> 9) & 1;
        int k    = t >> 10;
        int c = (lane >> 4) * 8 + j;
        int d = half * 16 + (lane & 15);
        WB[t] = f2bf(W[k * 1024 + c * 32 + d]);
    }
    const int4 m1 = make_int4(-1, -1, -1, -1);
    for (int i = t; i < n4; i += gridDim.x * blockDim.x) child4[i] = m1;
}

// Inverse map: each point owns a unique (out,k) slot -> plain store.
__global__ __launch_bounds__(256) void build_map_kernel(
    const int* __restrict__ k_idx, const int* __restrict__ out_idx,
    int* __restrict__ child, int n) {
    int t = blockIdx.x * blockDim.x + threadIdx.x;
    if (t < n) child[(size_t)out_idx[t] * 8 + k_idx[t]] = t;
}

__global__ __launch_bounds__(256) void conv_gather_kernel(
    const float* __restrict__ x,
    const unsigned short* __restrict__ WB,
    const int* __restrict__ child,
    float* __restrict__ out,
    int num_out)
{
    const int lane  = threadIdx.x & 63;
    const int wv    = threadIdx.x >> 6;
    const int obase = (blockIdx.x * 4 + wv) * 16;     // 16 out voxels per wave
    if (obase >= num_out) return;

    const int row  = lane & 15;     // A-frag: m = lane&15 (out voxel in tile)
    const int quad = lane >> 4;     // A-frag: k-cols = quad*8 + j
    const int o = obase + row;

    // 8 child indices for this row (32B, 4 quads redundant -> L1-hot).
    int4 c0 = make_int4(-1, -1, -1, -1), c1 = make_int4(-1, -1, -1, -1);
    if (o < num_out) {
        const int4* cp = (const int4*)(child + (size_t)o * 8);
        c0 = cp[0]; c1 = cp[1];
    }
    int pk[8] = {c0.x, c0.y, c0.z, c0.w, c1.x, c1.y, c1.z, c1.w};

    // Issue all gathers up front (up to 8 x 32B per lane in flight).
    float4 xa[8], xb[8];
#pragma unroll
    for (int k = 0; k < 8; ++k) {
        xa[k] = make_float4(0.f, 0.f, 0.f, 0.f);
        xb[k] = make_float4(0.f, 0.f, 0.f, 0.f);
        if (pk[k] >= 0) {
            const float* xp = x + (size_t)pk[k] * 32 + quad * 8;
            xa[k] = *(const float4*)xp;
            xb[k] = *(const float4*)(xp + 4);
        }
    }

    f32x4 acc0 = {0.f, 0.f, 0.f, 0.f};   // channels 0..15
    f32x4 acc1 = {0.f, 0.f, 0.f, 0.f};   // channels 16..31

#pragma unroll
    for (int k = 0; k < 8; ++k) {
        ABFrag a;
        a.i[0] = pack2_bf16(xa[k].x, xa[k].y);
        a.i[1] = pack2_bf16(xa[k].z, xa[k].w);
        a.i[2] = pack2_bf16(xb[k].x, xb[k].y);
        a.i[3] = pack2_bf16(xb[k].z, xb[k].w);
        bf16x8 b0 = *(const bf16x8*)(WB + ((size_t)(k * 2 + 0) * 64 + lane) * 8);
        bf16x8 b1 = *(const bf16x8*)(WB + ((size_t)(k * 2 + 1) * 64 + lane) * 8);
        acc0 = __builtin_amdgcn_mfma_f32_16x16x32_bf16(a.v, b0, acc0, 0, 0, 0);
        acc1 = __builtin_amdgcn_mfma_f32_16x16x32_bf16(a.v, b1, acc1, 0, 0, 0);
    }

    // C/D layout: col = lane&15 (channel), row = quad*4 + r (voxel).
#pragma unroll
    for (int r = 0; r < 4; ++r) {
        int oo = obase + quad * 4 + r;
        if (oo < num_out) {
            float* op = out + (size_t)oo * 32 + (lane & 15);
            op[0]  = acc0[r];
            op[16] = acc1[r];
        }
    }
}

// ---- fallback (atomic scatter) in case ws_size can't hold the map ----
__global__ void prep_w_kernel(const float* __restrict__ W,
                              unsigned short* __restrict__ WB) {
    int t = blockIdx.x * blockDim.x + threadIdx.x;
    if (t >= 8 * 2 * 64 * 8) return;
    int j = t & 7, lane = (t >> 3) & 63, half = (t >> 9) & 1, k = t >> 10;
    int c = (lane >> 4) * 8 + j;
    int d = half * 16 + (lane & 15);
    WB[t] = f2bf(W[k * 1024 + c * 32 + d]);
}

__global__ __launch_bounds__(256) void conv_atomic_kernel(
    const float* __restrict__ x, const unsigned short* __restrict__ WB,
    const int* __restrict__ k_idx, const int* __restrict__ out_idx,
    float* __restrict__ out, int n)
{
    const int lane = threadIdx.x & 63;
    const int wv   = threadIdx.x >> 6;
    const int base = (blockIdx.x * 4 + wv) * 16;
    if (base >= n) return;
    const int row = lane & 15, quad = lane >> 4;
    const int p = base + row;
    int krow = -1;
    ABFrag a; a.i[0] = a.i[1] = a.i[2] = a.i[3] = 0;
    if (p < n) {
        krow = k_idx[p];
        const float* xp = x + (size_t)p * 32 + quad * 8;
        float4 x0 = *(const float4*)xp;
        float4 x1 = *(const float4*)(xp + 4);
        a.i[0] = pack2_bf16(x0.x, x0.y);
        a.i[1] = pack2_bf16(x0.z, x0.w);
        a.i[2] = pack2_bf16(x1.x, x1.y);
        a.i[3] = pack2_bf16(x1.z, x1.w);
    }
    f32x4 acc0 = {0.f,0.f,0.f,0.f}, acc1 = {0.f,0.f,0.f,0.f};
#pragma unroll
    for (int k = 0; k < 8; ++k) {
        bf16x8 b0 = *(const bf16x8*)(WB + ((size_t)(k*2+0)*64 + lane)*8);
        bf16x8 b1 = *(const bf16x8*)(WB + ((size_t)(k*2+1)*64 + lane)*8);
        const bool keep = (krow == k);
        ABFrag ak;
        ak.i[0] = keep ? a.i[0] : 0; ak.i[1] = keep ? a.i[1] : 0;
        ak.i[2] = keep ? a.i[2] : 0; ak.i[3] = keep ? a.i[3] : 0;
        acc0 = __builtin_amdgcn_mfma_f32_16x16x32_bf16(ak.v, b0, acc0, 0, 0, 0);
        acc1 = __builtin_amdgcn_mfma_f32_16x16x32_bf16(ak.v, b1, acc1, 0, 0, 0);
    }
#pragma unroll
    for (int r = 0; r < 4; ++r) {
        int p2 = base + quad * 4 + r;
        if (p2 < n) {
            int oi = out_idx[p2];
            float* op = out + (size_t)oi * 32 + (lane & 15);
            atomicAdd(op,      acc0[r]);
            atomicAdd(op + 16, acc1[r]);
        }
    }
}

extern "C" void kernel_launch(void* const* d_in, const int* in_sizes, int n_in,
                              void* d_out, int out_size, void* d_ws, size_t ws_size,
                              hipStream_t stream) {
    const float* x       = (const float*)d_in[0];
    const float* W       = (const float*)d_in[1];
    const int*   k_idx   = (const int*)d_in[2];
    const int*   out_idx = (const int*)d_in[3];
    const int n = in_sizes[2];
    const int num_out = out_size / 32;           // C=32 channels per voxel
    float* out = (float*)d_out;

    unsigned short* WB = (unsigned short*)d_ws;  // 16 KB repacked W
    const size_t wb_bytes = 16384;
    int* child = (int*)((char*)d_ws + wb_bytes); // num_out*8 ints
    const size_t child_bytes = (size_t)num_out * 8 * sizeof(int);

    if (ws_size >= wb_bytes + child_bytes) {
        // ---- atomic-free path: 3 launches ----
        int n4 = num_out * 2;                    // int4 count of child map
        int blocksA = (n4 + 255) / 256;
        if (blocksA < 32) blocksA = 32;          // prep needs 8192 threads
        prep_fill_kernel<<<blocksA, 256, 0, stream>>>(W, WB, (int4*)child, n4);
        build_map_kernel<<<(n + 255) / 256, 256, 0, stream>>>(k_idx, out_idx, child, n);
        int blocks = (num_out + 63) / 64;        // 64 voxels/block (4 waves)
        conv_gather_kernel<<<blocks, 256, 0, stream>>>(x, WB, child, out, num_out);
    } else {
        // ---- fallback: atomic scatter ----
        prep_w_kernel<<<32, 256, 0, stream>>>(W, WB);
        hipMemsetAsync(d_out, 0, (size_t)out_size * sizeof(float), stream);
        int blocks = (n + 63) / 64;
        conv_atomic_kernel<<<blocks, 256, 0, stream>>>(x, WB, k_idx, out_idx, out, n);
    }
}

// Round 4
// 183.920 us; speedup vs baseline: 1.0165x; 1.0165x over previous
//
#include <hip/hip_runtime.h>
#include <hip/hip_bf16.h>

// Sparse Conv3d(32,32,k=2,s=2) kernel-map form:
//   out[out_idx[p], d] += sum_c x[p,c] * W[k_idx[p], c, d]
//
// R4: atomic-free inverse-map design (child[o][k]=p built with plain stores;
// one wave per 16 output voxels; 16x16x32 bf16 MFMA per k; plain stores).
// Fix vs R3: at VGPR=56 the compiler sank the 16 gather loads into the k-loop
// -> 8 serialized dependent ~900-cyc loads per wave (59 us, 19% HBM, all idle).
// Now: __launch_bounds__(256,4) (VGPR budget ~128) + UNCONDITIONAL clamped
// gathers (no execz branches), zero invalid fragments via cndmask after load,
// so all 16 loads issue as one batch and stay in flight.

typedef __attribute__((ext_vector_type(8))) short bf16x8;   // 8 bf16 = 4 VGPRs
typedef __attribute__((ext_vector_type(4))) float f32x4;    // 4 fp32 acc

union ABFrag { bf16x8 v; int i[4]; };
union BFI { __hip_bfloat162 h; int i; };

__device__ __forceinline__ int pack2_bf16(float a, float b) {
    BFI u; u.h = __float22bfloat162_rn(make_float2(a, b));   // h.x=lo, h.y=hi
    return u.i;
}

__device__ __forceinline__ unsigned short f2bf(float f) {
    union { float f; unsigned u; } v; v.f = f;
    unsigned r = v.u + 0x7FFFu + ((v.u >> 16) & 1u);   // RNE
    return (unsigned short)(r >> 16);
}

// Fused: (a) repack W[k][c][d] fp32 -> WB in B-fragment lane order (16 KB):
// WB[((k*2+half)*64 + lane)*8 + j] = bf16(W[k][(lane>>4)*8+j][half*16+(lane&15)])
// (b) grid-stride fill of child map with -1 (int4 stores).
__global__ __launch_bounds__(256) void prep_fill_kernel(
    const float* __restrict__ W, unsigned short* __restrict__ WB,
    int4* __restrict__ child4, int n4) {
    int t = blockIdx.x * blockDim.x + threadIdx.x;
    if (t < 8 * 2 * 64 * 8) {
        int j    = t & 7;
        int lane = (t >> 3) & 63;
        int half = (t >> 9) & 1;
        int k    = t >> 10;
        int c = (lane >> 4) * 8 + j;
        int d = half * 16 + (lane & 15);
        WB[t] = f2bf(W[k * 1024 + c * 32 + d]);
    }
    const int4 m1 = make_int4(-1, -1, -1, -1);
    for (int i = t; i < n4; i += gridDim.x * blockDim.x) child4[i] = m1;
}

// Inverse map: each point owns a unique (out,k) slot -> plain store.
__global__ __launch_bounds__(256) void build_map_kernel(
    const int* __restrict__ k_idx, const int* __restrict__ out_idx,
    int* __restrict__ child, int n) {
    int t = blockIdx.x * blockDim.x + threadIdx.x;
    if (t < n) child[(size_t)out_idx[t] * 8 + k_idx[t]] = t;
}

__global__ __launch_bounds__(256, 4) void conv_gather_kernel(
    const float* __restrict__ x,
    const unsigned short* __restrict__ WB,
    const int* __restrict__ child,
    float* __restrict__ out,
    int num_out)
{
    const int lane  = threadIdx.x & 63;
    const int wv    = threadIdx.x >> 6;
    const int obase = (blockIdx.x * 4 + wv) * 16;     // 16 out voxels per wave
    if (obase >= num_out) return;

    const int row  = lane & 15;     // A-frag: m = lane&15 (out voxel in tile)
    const int quad = lane >> 4;     // A-frag: k-cols = quad*8 + j
    int o = obase + row;
    if (o >= num_out) o = num_out - 1;   // clamp (stores are guarded, not loads)

    // 8 child indices for this row (32B; 4 quads redundant -> L1-hot).
    const int4* cp = (const int4*)(child + (size_t)o * 8);
    int4 c0 = cp[0], c1 = cp[1];
    int pk[8] = {c0.x, c0.y, c0.z, c0.w, c1.x, c1.y, c1.z, c1.w};

    // Unconditional clamped gathers: all 16 loads issue as one batch.
    const float* xp0[8];
#pragma unroll
    for (int k = 0; k < 8; ++k) {
        int p = pk[k] < 0 ? 0 : pk[k];
        xp0[k] = x + (size_t)p * 32 + quad * 8;
    }
    float4 xa[8], xb[8];
#pragma unroll
    for (int k = 0; k < 8; ++k) {
        xa[k] = *(const float4*)(xp0[k]);
        xb[k] = *(const float4*)(xp0[k] + 4);
    }

    f32x4 acc0 = {0.f, 0.f, 0.f, 0.f};   // channels 0..15
    f32x4 acc1 = {0.f, 0.f, 0.f, 0.f};   // channels 16..31

#pragma unroll
    for (int k = 0; k < 8; ++k) {
        const bool valid = pk[k] >= 0;
        ABFrag a;
        a.i[0] = valid ? pack2_bf16(xa[k].x, xa[k].y) : 0;
        a.i[1] = valid ? pack2_bf16(xa[k].z, xa[k].w) : 0;
        a.i[2] = valid ? pack2_bf16(xb[k].x, xb[k].y) : 0;
        a.i[3] = valid ? pack2_bf16(xb[k].z, xb[k].w) : 0;
        bf16x8 b0 = *(const bf16x8*)(WB + ((size_t)(k * 2 + 0) * 64 + lane) * 8);
        bf16x8 b1 = *(const bf16x8*)(WB + ((size_t)(k * 2 + 1) * 64 + lane) * 8);
        acc0 = __builtin_amdgcn_mfma_f32_16x16x32_bf16(a.v, b0, acc0, 0, 0, 0);
        acc1 = __builtin_amdgcn_mfma_f32_16x16x32_bf16(a.v, b1, acc1, 0, 0, 0);
    }

    // C/D layout: col = lane&15 (channel), row = quad*4 + r (voxel).
#pragma unroll
    for (int r = 0; r < 4; ++r) {
        int oo = obase + quad * 4 + r;
        if (oo < num_out) {
            float* op = out + (size_t)oo * 32 + (lane & 15);
            op[0]  = acc0[r];
            op[16] = acc1[r];
        }
    }
}

// ---- fallback (atomic scatter) in case ws_size can't hold the map ----
__global__ void prep_w_kernel(const float* __restrict__ W,
                              unsigned short* __restrict__ WB) {
    int t = blockIdx.x * blockDim.x + threadIdx.x;
    if (t >= 8 * 2 * 64 * 8) return;
    int j = t & 7, lane = (t >> 3) & 63, half = (t >> 9) & 1, k = t >> 10;
    int c = (lane >> 4) * 8 + j;
    int d = half * 16 + (lane & 15);
    WB[t] = f2bf(W[k * 1024 + c * 32 + d]);
}

__global__ __launch_bounds__(256) void conv_atomic_kernel(
    const float* __restrict__ x, const unsigned short* __restrict__ WB,
    const int* __restrict__ k_idx, const int* __restrict__ out_idx,
    float* __restrict__ out, int n)
{
    const int lane = threadIdx.x & 63;
    const int wv   = threadIdx.x >> 6;
    const int base = (blockIdx.x * 4 + wv) * 16;
    if (base >= n) return;
    const int row = lane & 15, quad = lane >> 4;
    const int p = base + row;
    int krow = -1;
    ABFrag a; a.i[0] = a.i[1] = a.i[2] = a.i[3] = 0;
    if (p < n) {
        krow = k_idx[p];
        const float* xp = x + (size_t)p * 32 + quad * 8;
        float4 x0 = *(const float4*)xp;
        float4 x1 = *(const float4*)(xp + 4);
        a.i[0] = pack2_bf16(x0.x, x0.y);
        a.i[1] = pack2_bf16(x0.z, x0.w);
        a.i[2] = pack2_bf16(x1.x, x1.y);
        a.i[3] = pack2_bf16(x1.z, x1.w);
    }
    f32x4 acc0 = {0.f,0.f,0.f,0.f}, acc1 = {0.f,0.f,0.f,0.f};
#pragma unroll
    for (int k = 0; k < 8; ++k) {
        bf16x8 b0 = *(const bf16x8*)(WB + ((size_t)(k*2+0)*64 + lane)*8);
        bf16x8 b1 = *(const bf16x8*)(WB + ((size_t)(k*2+1)*64 + lane)*8);
        const bool keep = (krow == k);
        ABFrag ak;
        ak.i[0] = keep ? a.i[0] : 0; ak.i[1] = keep ? a.i[1] : 0;
        ak.i[2] = keep ? a.i[2] : 0; ak.i[3] = keep ? a.i[3] : 0;
        acc0 = __builtin_amdgcn_mfma_f32_16x16x32_bf16(ak.v, b0, acc0, 0, 0, 0);
        acc1 = __builtin_amdgcn_mfma_f32_16x16x32_bf16(ak.v, b1, acc1, 0, 0, 0);
    }
#pragma unroll
    for (int r = 0; r < 4; ++r) {
        int p2 = base + quad * 4 + r;
        if (p2 < n) {
            int oi = out_idx[p2];
            float* op = out + (size_t)oi * 32 + (lane & 15);
            atomicAdd(op,      acc0[r]);
            atomicAdd(op + 16, acc1[r]);
        }
    }
}

extern "C" void kernel_launch(void* const* d_in, const int* in_sizes, int n_in,
                              void* d_out, int out_size, void* d_ws, size_t ws_size,
                              hipStream_t stream) {
    const float* x       = (const float*)d_in[0];
    const float* W       = (const float*)d_in[1];
    const int*   k_idx   = (const int*)d_in[2];
    const int*   out_idx = (const int*)d_in[3];
    const int n = in_sizes[2];
    const int num_out = out_size / 32;           // C=32 channels per voxel
    float* out = (float*)d_out;

    unsigned short* WB = (unsigned short*)d_ws;  // 16 KB repacked W
    const size_t wb_bytes = 16384;
    int* child = (int*)((char*)d_ws + wb_bytes); // num_out*8 ints
    const size_t child_bytes = (size_t)num_out * 8 * sizeof(int);

    if (ws_size >= wb_bytes + child_bytes) {
        // ---- atomic-free path: 3 launches ----
        int n4 = num_out * 2;                    // int4 count of child map
        int blocksA = (n4 + 255) / 256;
        if (blocksA < 32) blocksA = 32;          // prep needs 8192 threads
        prep_fill_kernel<<<blocksA, 256, 0, stream>>>(W, WB, (int4*)child, n4);
        build_map_kernel<<<(n + 255) / 256, 256, 0, stream>>>(k_idx, out_idx, child, n);
        int blocks = (num_out + 63) / 64;        // 64 voxels/block (4 waves)
        conv_gather_kernel<<<blocks, 256, 0, stream>>>(x, WB, child, out, num_out);
    } else {
        // ---- fallback: atomic scatter ----
        prep_w_kernel<<<32, 256, 0, stream>>>(W, WB);
        hipMemsetAsync(d_out, 0, (size_t)out_size * sizeof(float), stream);
        int blocks = (n + 63) / 64;
        conv_atomic_kernel<<<blocks, 256, 0, stream>>>(x, WB, k_idx, out_idx, out, n);
    }
}